// Round 1
// baseline (11.102 us; speedup 1.0000x reference)
//
#include <hip/hip_runtime.h>

// DWT_1D (Haar, band length 2): Lo[m] = (x[2m]+x[2m+1])/sqrt(2),
//                               Hi[m] = (x[2m]-x[2m+1])/sqrt(2)
// x: (8,64,8192) fp32 -> Lo,Hi: (8,64,4096) fp32, concatenated in d_out.
// The Toeplitz matrices in d_in[1]/d_in[2] are fixed Haar structure; unused.

#define INV_SQRT2 0.70710678118654752440f

__global__ __launch_bounds__(256) void dwt1d_haar_kernel(
    const float4* __restrict__ x4,   // input viewed as float4, 2 per thread
    float4* __restrict__ lo4,        // d_out first half  (float4 view)
    float4* __restrict__ hi4,        // d_out second half (float4 view)
    int n4)                          // number of float4 outputs per half
{
    int t = blockIdx.x * blockDim.x + threadIdx.x;
    if (t >= n4) return;

    // 8 consecutive input floats -> 4 Lo + 4 Hi outputs
    float4 a = x4[2 * t + 0];
    float4 b = x4[2 * t + 1];

    float4 lo, hi;
    lo.x = (a.x + a.y) * INV_SQRT2;
    lo.y = (a.z + a.w) * INV_SQRT2;
    lo.z = (b.x + b.y) * INV_SQRT2;
    lo.w = (b.z + b.w) * INV_SQRT2;

    hi.x = (a.x - a.y) * INV_SQRT2;
    hi.y = (a.z - a.w) * INV_SQRT2;
    hi.z = (b.x - b.y) * INV_SQRT2;
    hi.w = (b.z - b.w) * INV_SQRT2;

    lo4[t] = lo;
    hi4[t] = hi;
}

extern "C" void kernel_launch(void* const* d_in, const int* in_sizes, int n_in,
                              void* d_out, int out_size, void* d_ws, size_t ws_size,
                              hipStream_t stream) {
    const float* x = (const float*)d_in[0];
    float* out = (float*)d_out;

    // out_size = 2 * half  (Lo then Hi, each 8*64*4096 floats)
    const int half = out_size / 2;           // 2,097,152
    const int n4   = half / 4;               // 524,288 float4 outputs per half

    float4* lo4 = (float4*)out;
    float4* hi4 = (float4*)(out + half);
    const float4* x4 = (const float4*)x;

    const int block = 256;
    const int grid  = (n4 + block - 1) / block;  // 2048
    dwt1d_haar_kernel<<<grid, block, 0, stream>>>(x4, lo4, hi4, n4);
}